// Round 2
// baseline (3865.808 us; speedup 1.0000x reference)
//
#include <hip/hip_runtime.h>
#include <hip/hip_bf16.h>

#define NN 40000
#define EE 640000
#define CCH 128
#define GG 64

__device__ __forceinline__ float lrelu01(float v){ return v > 0.f ? v : 0.01f*v; }
__device__ __forceinline__ float sigm(float v){ return 1.f/(1.f + __expf(-v)); }
__device__ __forceinline__ float tanh_f(float v){
  v = fminf(fmaxf(v, -15.f), 15.f);
  const float t = __expf(2.f*v);
  return (t - 1.f)/(t + 1.f);
}
// dual-dtype loads: flags[0]=floats are f32, flags[1]=ints are i64
__device__ __forceinline__ float LDF(const void* p, int f32, size_t i){
  return f32 ? ((const float*)p)[i] : (float)((const __hip_bfloat16*)p)[i];
}
__device__ __forceinline__ int LDI(const void* p, int i64, size_t i){
  return i64 ? (int)((const long long*)p)[i] : ((const int*)p)[i];
}

// ---------------- dtype detection (device-side, graph-safe) ----------------
__global__ __launch_bounds__(256) void k_detect(const unsigned short* __restrict__ xh,
                                                const unsigned int* __restrict__ ei,
                                                int* __restrict__ flags){
  __shared__ int s1[256], s2[256];
  const int t = threadIdx.x;
  int c1 = 0, c2 = 0;
  for (int i=0;i<8;++i){
    const unsigned short w = xh[t*8 + i];          // bf16-implausible halfwords?
    const int e = (w >> 7) & 0xFF;
    if (e < 100 || e > 140) c1++;
    const unsigned int o = ei[(t*8 + i)*2 + 1];    // odd 32-bit words of edge_index
    if (o) c2++;
  }
  s1[t]=c1; s2[t]=c2; __syncthreads();
  for (int off=128; off; off>>=1){ if (t<off){ s1[t]+=s1[t+off]; s2[t]+=s2[t+off]; } __syncthreads(); }
  if (t==0){
    flags[0] = (s1[0] > 64) ? 1 : 0;   // f32 floats: ~850 implausible; bf16: ~0
    flags[1] = (s2[0] < 16) ? 1 : 0;   // i64 ints: all odd words 0; i32: ~2048 nonzero
  }
}

// ---------------- CSR build ----------------
__global__ __launch_bounds__(256) void k_hist(const void* __restrict__ eidx, const int* __restrict__ flags,
                                              int* __restrict__ deg){
  const int e = blockIdx.x*256 + threadIdx.x;
  if (e >= EE) return;
  atomicAdd(&deg[LDI(eidx, flags[1], (size_t)EE + e)], 1);
}

__global__ __launch_bounds__(1024) void k_scan(const int* __restrict__ deg, int* __restrict__ roff, int* __restrict__ pos){
  __shared__ int s[1024];
  const int t = threadIdx.x;
  const int base = t*40;
  int sum = 0;
  for (int i=0;i<40;++i){ const int idx = base+i; if (idx < NN) sum += deg[idx]; }
  s[t] = sum; __syncthreads();
  for (int off=1; off<1024; off<<=1){
    const int v = (t >= off) ? s[t-off] : 0;
    __syncthreads();
    s[t] += v;
    __syncthreads();
  }
  int run = (t==0) ? 0 : s[t-1];
  for (int i=0;i<40;++i){
    const int idx = base+i;
    if (idx < NN){ roff[idx] = run; pos[idx] = run; run += deg[idx]; }
  }
  if (t == 1023) roff[NN] = run;
}

__global__ __launch_bounds__(256) void k_scatter(const void* __restrict__ eidx, const void* __restrict__ ew,
                                                 const int* __restrict__ flags,
                                                 int* __restrict__ pos, int* __restrict__ es, float* __restrict__ ewt){
  const int e = blockIdx.x*256 + threadIdx.x;
  if (e >= EE) return;
  const int i64 = flags[1];
  const int d = LDI(eidx, i64, (size_t)EE + e);
  const int p = atomicAdd(&pos[d], 1);
  es[p] = LDI(eidx, i64, e);
  ewt[p] = LDF(ew, flags[0], e);
}

// ---------------- converts ----------------
__global__ __launch_bounds__(256) void k_x2f(const void* __restrict__ xin, const int* __restrict__ flags,
                                             float* __restrict__ xf){
  const int i = blockIdx.x*256 + threadIdx.x;
  if (i < NN*CCH) xf[i] = LDF(xin, flags[0], i);
}

__global__ __launch_bounds__(256) void k_batcvt(const void* __restrict__ batch, const int* __restrict__ flags,
                                                int* __restrict__ bat32){
  const int i = blockIdx.x*256 + threadIdx.x;
  if (i < NN) bat32[i] = LDI(batch, flags[1], i);
}

__global__ __launch_bounds__(256) void k_wcvt(const void* __restrict__ w, const int* __restrict__ flags,
                                              const size_t off, float* __restrict__ o, const int n){
  const int i = blockIdx.x*256 + threadIdx.x;
  if (i < n) o[i] = LDF(w, flags[0], off + i);
}

// (384,128) row-major -> transposed f32 [128][384]
__global__ __launch_bounds__(256) void k_wgruT(const void* __restrict__ w, const int* __restrict__ flags,
                                               const size_t off, float* __restrict__ o){
  const int i = blockIdx.x*256 + threadIdx.x;
  if (i >= 384*CCH) return;
  const int k = i / 384, j = i - k*384;
  o[i] = LDF(w, flags[0], off + (size_t)j*CCH + k);
}

// ---------------- m = x @ W  (W f32, [k][j] layout) ----------------
__global__ __launch_bounds__(256) void k_gemm_m(const float* __restrict__ x, const float* __restrict__ wf, float* __restrict__ m){
  __shared__ float s_x[32*CCH];
  __shared__ float s_w[32*CCH];
  const int tid = threadIdx.x;
  const int node0 = blockIdx.x * 32;
  {
    const float4* gx = (const float4*)(x + (size_t)node0*CCH);
    float4* sx = (float4*)s_x;
#pragma unroll
    for (int r=0;r<4;++r) sx[tid + r*256] = gx[tid + r*256];
  }
  const int ch0 = (tid & 31)*4;
  const int ln0 = (tid >> 5)*4;
  float acc[4][4] = {};
  for (int kc=0; kc<CCH; kc+=32){
    {
      const float4* gw = (const float4*)(wf + kc*CCH);
      float4* sw = (float4*)s_w;
#pragma unroll
      for (int r=0;r<4;++r) sw[tid + r*256] = gw[tid + r*256];
    }
    __syncthreads();
#pragma unroll
    for (int kl=0; kl<32; ++kl){
      const float4 wv = *(const float4*)(s_w + kl*CCH + ch0);
      const int kg = kc + kl;
#pragma unroll
      for (int i=0;i<4;++i){
        const float xv = s_x[(ln0+i)*CCH + kg];
        acc[i][0] += xv*wv.x; acc[i][1] += xv*wv.y; acc[i][2] += xv*wv.z; acc[i][3] += xv*wv.w;
      }
    }
    __syncthreads();
  }
#pragma unroll
  for (int i=0;i<4;++i){
    float4 v; v.x=acc[i][0]; v.y=acc[i][1]; v.z=acc[i][2]; v.w=acc[i][3];
    *(float4*)(m + (size_t)(node0+ln0+i)*CCH + ch0) = v;
  }
}

// ---------------- agg[dst] = sum ew * m[src] ----------------
__global__ __launch_bounds__(256) void k_agg(const float* __restrict__ m, const int* __restrict__ roff,
                                             const int* __restrict__ es, const float* __restrict__ ewt,
                                             float* __restrict__ agg, const int useW){
  const int node = (blockIdx.x*256 + threadIdx.x) >> 6;
  const int lane = threadIdx.x & 63;
  if (node >= NN) return;
  const int beg = roff[node], end = roff[node+1];
  float ax = 0.f, ay = 0.f;
  int e = beg;
  for (; e + 1 < end; e += 2){
    const int s0 = es[e], s1 = es[e+1];
    const float w0 = useW ? ewt[e] : 1.f;
    const float w1 = useW ? ewt[e+1] : 1.f;
    const float2 v0 = *(const float2*)(m + (size_t)s0*CCH + lane*2);
    const float2 v1 = *(const float2*)(m + (size_t)s1*CCH + lane*2);
    ax += w0*v0.x + w1*v1.x;
    ay += w0*v0.y + w1*v1.y;
  }
  if (e < end){
    const int s0 = es[e];
    const float w0 = useW ? ewt[e] : 1.f;
    const float2 v0 = *(const float2*)(m + (size_t)s0*CCH + lane*2);
    ax += w0*v0.x; ay += w0*v0.y;
  }
  float2 ov; ov.x = ax; ov.y = ay;
  *(float2*)(agg + (size_t)node*CCH + lane*2) = ov;
}

// ---------------- fused GRU: x = GRU(agg, x) ----------------
__global__ __launch_bounds__(256) void k_gru(const float* __restrict__ agg, float* __restrict__ x,
    const float* __restrict__ wiT, const float* __restrict__ whT,
    const void* __restrict__ bih, const void* __restrict__ bhh,
    const size_t boff, const int* __restrict__ flags){
  __shared__ float s_agg[16*CCH];
  __shared__ float s_x[16*CCH];
  __shared__ float s_wi[8*384];
  __shared__ float s_wh[8*384];
  const int tid = threadIdx.x;
  const int node0 = blockIdx.x*16;
  const int f32 = flags[0];
  {
    const float4* ga = (const float4*)(agg + (size_t)node0*CCH);
    const float4* gx = (const float4*)(x + (size_t)node0*CCH);
    float4* sa = (float4*)s_agg; float4* sx = (float4*)s_x;
    sa[tid] = ga[tid]; sa[tid+256] = ga[tid+256];
    sx[tid] = gx[tid]; sx[tid+256] = gx[tid+256];
  }
  const int ch0 = (tid & 31)*4;
  const int ln0 = (tid >> 5)*2;
  float ai[3][2][4] = {};
  float ah[3][2][4] = {};
  for (int kc=0; kc<CCH; kc+=8){
    {
      const float4* gwi = (const float4*)(wiT + kc*384);
      const float4* gwh = (const float4*)(whT + kc*384);
      float4* swi = (float4*)s_wi; float4* swh = (float4*)s_wh;
#pragma unroll
      for (int r=0;r<3;++r){ swi[tid + r*256] = gwi[tid + r*256]; swh[tid + r*256] = gwh[tid + r*256]; }
    }
    __syncthreads();
#pragma unroll
    for (int kl=0; kl<8; ++kl){
      const int kg = kc + kl;
      const float a0 = s_agg[ln0*CCH + kg];
      const float a1 = s_agg[(ln0+1)*CCH + kg];
      const float h0 = s_x[ln0*CCH + kg];
      const float h1 = s_x[(ln0+1)*CCH + kg];
#pragma unroll
      for (int g=0; g<3; ++g){
        const float4 wi = *(const float4*)(s_wi + kl*384 + g*CCH + ch0);
        const float4 wh = *(const float4*)(s_wh + kl*384 + g*CCH + ch0);
        ai[g][0][0] += a0*wi.x; ai[g][0][1] += a0*wi.y; ai[g][0][2] += a0*wi.z; ai[g][0][3] += a0*wi.w;
        ai[g][1][0] += a1*wi.x; ai[g][1][1] += a1*wi.y; ai[g][1][2] += a1*wi.z; ai[g][1][3] += a1*wi.w;
        ah[g][0][0] += h0*wh.x; ah[g][0][1] += h0*wh.y; ah[g][0][2] += h0*wh.z; ah[g][0][3] += h0*wh.w;
        ah[g][1][0] += h1*wh.x; ah[g][1][1] += h1*wh.y; ah[g][1][2] += h1*wh.z; ah[g][1][3] += h1*wh.w;
      }
    }
    __syncthreads();
  }
  float bi[3][4], bh[3][4];
#pragma unroll
  for (int g=0; g<3; ++g)
#pragma unroll
    for (int c=0;c<4;++c){
      bi[g][c] = LDF(bih, f32, boff + g*CCH + ch0 + c);
      bh[g][c] = LDF(bhh, f32, boff + g*CCH + ch0 + c);
    }
#pragma unroll
  for (int u=0; u<2; ++u){
    const int ln = ln0 + u;
    float res[4];
#pragma unroll
    for (int c=0;c<4;++c){
      const float rr = sigm(ai[0][u][c] + ah[0][u][c] + bi[0][c] + bh[0][c]);
      const float zz = sigm(ai[1][u][c] + ah[1][u][c] + bi[1][c] + bh[1][c]);
      const float hn = ah[2][u][c] + bh[2][c];
      const float nv = tanh_f(ai[2][u][c] + bi[2][c] + rr*hn);
      const float h  = s_x[ln*CCH + ch0 + c];
      res[c] = (1.f - zz)*nv + zz*h;
    }
    float4 v; v.x=res[0]; v.y=res[1]; v.z=res[2]; v.w=res[3];
    *(float4*)(x + (size_t)(node0+ln)*CCH + ch0) = v;
  }
}

// ---------------- GraphNorm ----------------
__global__ __launch_bounds__(256) void k_gn_stats(const float* __restrict__ x, float* __restrict__ accum, const int pre){
  const int tid = threadIdx.x;
  const int ch = tid & 127;
  const int half = tid >> 7;
  const int node0 = blockIdx.x * 128;
  float s = 0.f, s2 = 0.f;
  for (int r = half; r < 128; r += 2){
    const int n = node0 + r;
    if (n >= NN) break;
    float v = x[(size_t)n*CCH + ch];
    if (pre) v = lrelu01(v);
    s += v; s2 += v*v;
  }
  __shared__ float buf[256];
  buf[tid] = s; __syncthreads();
  if (tid < 128) atomicAdd(&accum[ch], buf[tid] + buf[tid+128]);
  __syncthreads();
  buf[tid] = s2; __syncthreads();
  if (tid < 128) atomicAdd(&accum[128+ch], buf[tid] + buf[tid+128]);
}

__global__ void k_gn_final(const float* __restrict__ accum, const void* __restrict__ gw,
                           const void* __restrict__ gb, const void* __restrict__ gms,
                           const size_t off, const int* __restrict__ flags, float* __restrict__ par){
  const int j = threadIdx.x;
  const int f32 = flags[0];
  const float inv = 1.f/(float)NN;
  const float mean = accum[j]*inv;
  const float m2 = accum[128+j]*inv;
  const float ms = LDF(gms, f32, off + j);
  const float var = m2 - 2.f*ms*mean*mean + ms*ms*mean*mean;
  const float sc = LDF(gw, f32, off + j) / sqrtf(var + 1e-5f);
  par[j] = sc;
  par[128+j] = LDF(gb, f32, off + j) - sc*ms*mean;
}

// mode 0: lrelu(a*x+c)   mode 1: a*lrelu(x)+c
__global__ __launch_bounds__(256) void k_gn_apply(float* __restrict__ x, const float* __restrict__ par, const int mode){
  const int i = blockIdx.x*256 + threadIdx.x;
#pragma unroll
  for (int r=0;r<8;++r){
    const int idx = i + r*640000;
    float v = x[idx];
    const int ch = idx & 127;
    if (mode == 1) v = lrelu01(v);
    v = par[ch]*v + par[128+ch];
    if (mode == 0) v = lrelu01(v);
    x[idx] = v;
  }
}

// ---------------- final: lrelu + segment sum ----------------
__global__ __launch_bounds__(256) void k_final(const float* __restrict__ x, const int* __restrict__ bat32, float* __restrict__ outf){
  const int idx = blockIdx.x*256 + threadIdx.x;
  const int n = idx >> 7, ch = idx & 127;
  const float v = lrelu01(x[idx]);
  atomicAdd(&outf[bat32[n]*CCH + ch], v);
}

__global__ __launch_bounds__(256) void k_store(const float* __restrict__ outf, const int* __restrict__ flags, void* __restrict__ out){
  const int i = blockIdx.x*256 + threadIdx.x;
  if (i >= GG*CCH) return;
  if (flags[0]) ((float*)out)[i] = outf[i];
  else ((__hip_bfloat16*)out)[i] = __float2bfloat16(outf[i]);
}

extern "C" void kernel_launch(void* const* d_in, const int* in_sizes, int n_in,
                              void* d_out, int out_size, void* d_ws, size_t ws_size,
                              hipStream_t stream){
  const void* x_in = d_in[0];
  const void* ew   = d_in[1];
  const void* cw   = d_in[2];
  const void* wih  = d_in[3];
  const void* whh  = d_in[4];
  const void* bih  = d_in[5];
  const void* bhh  = d_in[6];
  const void* gnw  = d_in[7];
  const void* gnb  = d_in[8];
  const void* gnms = d_in[9];
  const void* eidx  = d_in[10];
  const void* batch = d_in[11];

  float* base = (float*)d_ws;
  size_t o = 0;
  float* xbuf   = base + o; o += (size_t)NN*CCH;
  float* mbuf   = base + o; o += (size_t)NN*CCH;
  float* aggbuf = base + o; o += (size_t)NN*CCH;
  float* ewt    = base + o; o += EE;
  float* wconvf = base + o; o += CCH*CCH;
  float* wiT    = base + o; o += 384*CCH;
  float* whT    = base + o; o += 384*CCH;
  float* gnpar  = base + o; o += 256;
  int* flags    = (int*)(base + o); o += 2;
  int* bat32    = (int*)(base + o); o += NN;
  // ---- zero zone (one memset covers outf + gnacc + deg) ----
  float* outf   = base + o; o += GG*CCH;   // 8192
  float* gnacc  = base + o; o += 1024;     // 4 layers x 256
  int* deg      = (int*)(base + o); o += NN;
  // ---- end zero zone ----
  int* roff     = (int*)(base + o); o += NN+1;
  int* pos      = (int*)(base + o); o += NN;
  int* es       = (int*)(base + o); o += EE;

  hipMemsetAsync(outf, 0, (size_t)(GG*CCH + 1024 + NN)*4, stream);

  k_detect<<<1,256,0,stream>>>((const unsigned short*)x_in, (const unsigned int*)eidx, flags);
  k_hist<<<2500,256,0,stream>>>(eidx, flags, deg);
  k_scan<<<1,1024,0,stream>>>(deg, roff, pos);
  k_scatter<<<2500,256,0,stream>>>(eidx, ew, flags, pos, es, ewt);
  k_x2f<<<20000,256,0,stream>>>(x_in, flags, xbuf);
  k_batcvt<<<157,256,0,stream>>>(batch, flags, bat32);

  const int steps[5] = {5,4,3,2,1};
  for (int L=0; L<5; ++L){
    k_wgruT<<<192,256,0,stream>>>(wih, flags, (size_t)L*384*CCH, wiT);
    k_wgruT<<<192,256,0,stream>>>(whh, flags, (size_t)L*384*CCH, whT);
    for (int s=0; s<steps[L]; ++s){
      k_wcvt<<<64,256,0,stream>>>(cw, flags, (size_t)(L*5+s)*CCH*CCH, wconvf, CCH*CCH);
      k_gemm_m<<<1250,256,0,stream>>>(xbuf, wconvf, mbuf);
      k_agg<<<10000,256,0,stream>>>(mbuf, roff, es, ewt, aggbuf, (L<4) ? 1 : 0);
      k_gru<<<2500,256,0,stream>>>(aggbuf, xbuf, wiT, whT, bih, bhh, (size_t)L*384, flags);
    }
    if (L < 4){
      const int pre = (L==0) ? 0 : 1;
      k_gn_stats<<<313,256,0,stream>>>(xbuf, gnacc + L*256, pre);
      k_gn_final<<<1,128,0,stream>>>(gnacc + L*256, gnw, gnb, gnms, (size_t)L*CCH, flags, gnpar);
      k_gn_apply<<<2500,256,0,stream>>>(xbuf, gnpar, pre);
    }
  }
  k_final<<<20000,256,0,stream>>>(xbuf, bat32, outf);
  k_store<<<32,256,0,stream>>>(outf, flags, (__hip_bfloat16*)d_out);
}

// Round 4
// 2790.496 us; speedup vs baseline: 1.3853x; 1.3853x over previous
//
#include <hip/hip_runtime.h>
#include <hip/hip_bf16.h>

#define NN 40000
#define EE 640000
#define CCH 128
#define GG 64

typedef __attribute__((ext_vector_type(8))) short short8;
typedef __attribute__((ext_vector_type(4))) float f32x4;

__device__ __forceinline__ float lrelu01(float v){ return v > 0.f ? v : 0.01f*v; }
__device__ __forceinline__ float sigm(float v){ return 1.f/(1.f + __expf(-v)); }
__device__ __forceinline__ float tanh_f(float v){
  v = fminf(fmaxf(v, -15.f), 15.f);
  const float t = __expf(2.f*v);
  return (t - 1.f)/(t + 1.f);
}
__device__ __forceinline__ unsigned short f2bf(float f){
  union { float f; unsigned int u; } v; v.f = f;
  const unsigned int r = v.u + 0x7FFFu + ((v.u >> 16) & 1u);
  return (unsigned short)(r >> 16);
}
__device__ __forceinline__ float bf2f(unsigned short h){
  union { unsigned int u; float f; } v; v.u = ((unsigned int)h) << 16;
  return v.f;
}
// split 8 consecutive fp32 into bf16 hi + lo fragments (x = hi + lo, ~2^-18 rel err)
__device__ __forceinline__ void split_bf(const float* __restrict__ p, short8& hi, short8& lo){
  const float4 a = *(const float4*)p;
  const float4 b = *(const float4*)(p + 4);
  const float v[8] = {a.x,a.y,a.z,a.w,b.x,b.y,b.z,b.w};
#pragma unroll
  for (int i=0;i<8;++i){
    const unsigned short h = f2bf(v[i]);
    hi[i] = (short)h;
    lo[i] = (short)f2bf(v[i] - bf2f(h));
  }
}
// dual-dtype loads: flags[0]=floats are f32, flags[1]=ints are i64
__device__ __forceinline__ float LDF(const void* p, int f32, size_t i){
  return f32 ? ((const float*)p)[i] : bf2f(((const unsigned short*)p)[i]);
}
__device__ __forceinline__ int LDI(const void* p, int i64, size_t i){
  return i64 ? (int)((const long long*)p)[i] : ((const int*)p)[i];
}

// ---------------- dtype detection (device-side, graph-safe) ----------------
__global__ __launch_bounds__(256) void k_detect(const unsigned short* __restrict__ xh,
                                                const unsigned int* __restrict__ ei,
                                                int* __restrict__ flags){
  __shared__ int s1[256], s2[256];
  const int t = threadIdx.x;
  int c1 = 0, c2 = 0;
  for (int i=0;i<8;++i){
    const unsigned short w = xh[t*8 + i];
    const int e = (w >> 7) & 0xFF;
    if (e < 100 || e > 140) c1++;
    const unsigned int o = ei[(t*8 + i)*2 + 1];
    if (o) c2++;
  }
  s1[t]=c1; s2[t]=c2; __syncthreads();
  for (int off=128; off; off>>=1){ if (t<off){ s1[t]+=s1[t+off]; s2[t]+=s2[t+off]; } __syncthreads(); }
  if (t==0){
    flags[0] = (s1[0] > 64) ? 1 : 0;
    flags[1] = (s2[0] < 16) ? 1 : 0;
  }
}

// ---------------- CSR build ----------------
__global__ __launch_bounds__(256) void k_hist(const void* __restrict__ eidx, const int* __restrict__ flags,
                                              int* __restrict__ deg){
  const int e = blockIdx.x*256 + threadIdx.x;
  if (e >= EE) return;
  atomicAdd(&deg[LDI(eidx, flags[1], (size_t)EE + e)], 1);
}

__global__ __launch_bounds__(1024) void k_scan(const int* __restrict__ deg, int* __restrict__ roff, int* __restrict__ pos){
  __shared__ int s[1024];
  const int t = threadIdx.x;
  const int base = t*40;
  int sum = 0;
  for (int i=0;i<40;++i){ const int idx = base+i; if (idx < NN) sum += deg[idx]; }
  s[t] = sum; __syncthreads();
  for (int off=1; off<1024; off<<=1){
    const int v = (t >= off) ? s[t-off] : 0;
    __syncthreads();
    s[t] += v;
    __syncthreads();
  }
  int run = (t==0) ? 0 : s[t-1];
  for (int i=0;i<40;++i){
    const int idx = base+i;
    if (idx < NN){ roff[idx] = run; pos[idx] = run; run += deg[idx]; }
  }
  if (t == 1023) roff[NN] = run;
}

__global__ __launch_bounds__(256) void k_scatter(const void* __restrict__ eidx, const void* __restrict__ ew,
                                                 const int* __restrict__ flags,
                                                 int* __restrict__ pos, int* __restrict__ es, float* __restrict__ ewt){
  const int e = blockIdx.x*256 + threadIdx.x;
  if (e >= EE) return;
  const int i64 = flags[1];
  const int d = LDI(eidx, i64, (size_t)EE + e);
  const int p = atomicAdd(&pos[d], 1);
  es[p] = LDI(eidx, i64, e);
  ewt[p] = LDF(ew, flags[0], e);
}

// ---------------- converts ----------------
__global__ __launch_bounds__(256) void k_x2f(const void* __restrict__ xin, const int* __restrict__ flags,
                                             float* __restrict__ xf){
  const int i = blockIdx.x*256 + threadIdx.x;
  if (i < NN*CCH) xf[i] = LDF(xin, flags[0], i);
}

__global__ __launch_bounds__(256) void k_batcvt(const void* __restrict__ batch, const int* __restrict__ flags,
                                                int* __restrict__ bat32){
  const int i = blockIdx.x*256 + threadIdx.x;
  if (i < NN) bat32[i] = LDI(batch, flags[1], i);
}

// convert any float tensor to bf16 bits (straight copy; exact when input is bf16)
__global__ __launch_bounds__(256) void k_wcvt_bf(const void* __restrict__ w, const int* __restrict__ flags,
                                                 const size_t off, unsigned short* __restrict__ o, const int n){
  const int i = blockIdx.x*256 + threadIdx.x;
  if (i < n) o[i] = f2bf(LDF(w, flags[0], off + i));
}

// conv W (128x128 row-major [k][c]) -> WT bf16 [c][k]
__global__ __launch_bounds__(256) void k_wconvT(const void* __restrict__ w, const int* __restrict__ flags,
                                                const size_t off, unsigned short* __restrict__ o){
  const int i = blockIdx.x*256 + threadIdx.x;
  if (i >= CCH*CCH) return;
  const int c = i >> 7, k = i & 127;
  o[i] = f2bf(LDF(w, flags[0], off + (size_t)k*CCH + c));
}

// ---------------- m = xf @ convWT (MFMA, hi/lo split A), out m fp32 ----------------
// 16 nodes per wave, 64 per block, grid 625 (exact: 625*64 = 40000)
__global__ __launch_bounds__(256) void k_gemm_m(const float* __restrict__ xf,
                                                const unsigned short* __restrict__ wT,
                                                float* __restrict__ m){
  const int wv = threadIdx.x >> 6;
  const int lane = threadIdx.x & 63;
  const int quad = lane >> 4;
  const int ln = lane & 15;
  const int m0 = blockIdx.x*64 + wv*16;
  short8 fah[4], fal[4];
  {
    const float* p = xf + (size_t)(m0 + ln)*CCH + quad*8;
#pragma unroll
    for (int kk=0;kk<4;++kk) split_bf(p + kk*32, fah[kk], fal[kk]);
  }
#pragma unroll
  for (int ct=0; ct<8; ++ct){
    f32x4 acc = {0.f,0.f,0.f,0.f};
    const unsigned short* pw = wT + (size_t)(ct*16 + ln)*CCH + quad*8;
#pragma unroll
    for (int kk=0;kk<4;++kk){
      const short8 fb = *(const short8*)(pw + kk*32);
      acc = __builtin_amdgcn_mfma_f32_16x16x32_bf16(fah[kk], fb, acc, 0, 0, 0);
      acc = __builtin_amdgcn_mfma_f32_16x16x32_bf16(fal[kk], fb, acc, 0, 0, 0);
    }
    const int col = ct*16 + ln;
#pragma unroll
    for (int r=0;r<4;++r)
      m[(size_t)(m0 + quad*4 + r)*CCH + col] = acc[r];
  }
}

// ---------------- agg[dst] = sum ew * m[src]  (fp32 in/out) ----------------
__global__ __launch_bounds__(256) void k_agg(const float* __restrict__ m, const int* __restrict__ roff,
                                             const int* __restrict__ es, const float* __restrict__ ewt,
                                             float* __restrict__ agg, const int useW){
  const int node = (blockIdx.x*256 + threadIdx.x) >> 6;
  const int lane = threadIdx.x & 63;
  if (node >= NN) return;
  const int beg = roff[node], end = roff[node+1];
  float ax = 0.f, ay = 0.f;
  int e = beg;
  for (; e + 1 < end; e += 2){
    const int s0 = es[e], s1 = es[e+1];
    const float w0 = useW ? ewt[e] : 1.f;
    const float w1 = useW ? ewt[e+1] : 1.f;
    const float2 v0 = *(const float2*)(m + (size_t)s0*CCH + lane*2);
    const float2 v1 = *(const float2*)(m + (size_t)s1*CCH + lane*2);
    ax += w0*v0.x + w1*v1.x;
    ay += w0*v0.y + w1*v1.y;
  }
  if (e < end){
    const int s0 = es[e];
    const float w0 = useW ? ewt[e] : 1.f;
    const float2 v0 = *(const float2*)(m + (size_t)s0*CCH + lane*2);
    ax += w0*v0.x; ay += w0*v0.y;
  }
  float2 ov; ov.x = ax; ov.y = ay;
  *(float2*)(agg + (size_t)node*CCH + lane*2) = ov;
}

// ---------------- fused GRU via MFMA (hi/lo split A): x = GRU(agg, x) ----------------
// 16 nodes per wave, 64 per block, grid 625
__global__ __launch_bounds__(256) void k_gru(const float* __restrict__ agg,
                                             float* __restrict__ xf,
                                             const unsigned short* __restrict__ wiB,  // [384][128] bf16 (Bt)
                                             const unsigned short* __restrict__ whB,  // [384][128] bf16 (Bt)
                                             const void* __restrict__ bih, const void* __restrict__ bhh,
                                             const size_t boff, const int* __restrict__ flags){
  const int wv = threadIdx.x >> 6;
  const int lane = threadIdx.x & 63;
  const int quad = lane >> 4;
  const int ln = lane & 15;
  const int m0 = blockIdx.x*64 + wv*16;
  const int f32 = flags[0];
  short8 fah[4], fal[4], fxh[4], fxl[4];
  {
    const float* pa = agg + (size_t)(m0 + ln)*CCH + quad*8;
    const float* px = xf  + (size_t)(m0 + ln)*CCH + quad*8;
#pragma unroll
    for (int kk=0;kk<4;++kk){
      split_bf(pa + kk*32, fah[kk], fal[kk]);
      split_bf(px + kk*32, fxh[kk], fxl[kk]);
    }
  }
#pragma unroll 1
  for (int ct=0; ct<8; ++ct){
    f32x4 acc[6];
#pragma unroll
    for (int g=0;g<6;++g) acc[g] = (f32x4){0.f,0.f,0.f,0.f};
    const int col = ct*16 + ln;
#pragma unroll
    for (int kk=0;kk<4;++kk){
#pragma unroll
      for (int g=0;g<3;++g){
        const short8 fbi = *(const short8*)(wiB + (size_t)(g*CCH + col)*CCH + kk*32 + quad*8);
        const short8 fbh = *(const short8*)(whB + (size_t)(g*CCH + col)*CCH + kk*32 + quad*8);
        acc[g]   = __builtin_amdgcn_mfma_f32_16x16x32_bf16(fah[kk], fbi, acc[g], 0, 0, 0);
        acc[g]   = __builtin_amdgcn_mfma_f32_16x16x32_bf16(fal[kk], fbi, acc[g], 0, 0, 0);
        acc[3+g] = __builtin_amdgcn_mfma_f32_16x16x32_bf16(fxh[kk], fbh, acc[3+g], 0, 0, 0);
        acc[3+g] = __builtin_amdgcn_mfma_f32_16x16x32_bf16(fxl[kk], fbh, acc[3+g], 0, 0, 0);
      }
    }
    float bi[3], bh[3];
#pragma unroll
    for (int g=0;g<3;++g){
      bi[g] = LDF(bih, f32, boff + g*CCH + col);
      bh[g] = LDF(bhh, f32, boff + g*CCH + col);
    }
#pragma unroll
    for (int r=0;r<4;++r){
      const int row = m0 + quad*4 + r;
      const size_t idx = (size_t)row*CCH + col;
      const float h = xf[idx];
      const float rr = sigm(acc[0][r] + acc[3][r] + bi[0] + bh[0]);
      const float zz = sigm(acc[1][r] + acc[4][r] + bi[1] + bh[1]);
      const float nv = tanh_f(acc[2][r] + bi[2] + rr*(acc[5][r] + bh[2]));
      xf[idx] = (1.f - zz)*nv + zz*h;
    }
  }
}

// ---------------- GraphNorm ----------------
__global__ __launch_bounds__(256) void k_gn_stats(const float* __restrict__ x, float* __restrict__ accum, const int pre){
  const int tid = threadIdx.x;
  const int ch = tid & 127;
  const int half = tid >> 7;
  const int node0 = blockIdx.x * 128;
  float s = 0.f, s2 = 0.f;
  for (int r = half; r < 128; r += 2){
    const int n = node0 + r;
    if (n >= NN) break;
    float v = x[(size_t)n*CCH + ch];
    if (pre) v = lrelu01(v);
    s += v; s2 += v*v;
  }
  __shared__ float buf[256];
  buf[tid] = s; __syncthreads();
  if (tid < 128) atomicAdd(&accum[ch], buf[tid] + buf[tid+128]);
  __syncthreads();
  buf[tid] = s2; __syncthreads();
  if (tid < 128) atomicAdd(&accum[128+ch], buf[tid] + buf[tid+128]);
}

__global__ void k_gn_final(const float* __restrict__ accum, const void* __restrict__ gw,
                           const void* __restrict__ gb, const void* __restrict__ gms,
                           const size_t off, const int* __restrict__ flags, float* __restrict__ par){
  const int j = threadIdx.x;
  const int f32 = flags[0];
  const float inv = 1.f/(float)NN;
  const float mean = accum[j]*inv;
  const float m2 = accum[128+j]*inv;
  const float ms = LDF(gms, f32, off + j);
  const float var = m2 - 2.f*ms*mean*mean + ms*ms*mean*mean;
  const float sc = LDF(gw, f32, off + j) / sqrtf(var + 1e-5f);
  par[j] = sc;
  par[128+j] = LDF(gb, f32, off + j) - sc*ms*mean;
}

// mode 0: lrelu(a*x+c)   mode 1: a*lrelu(x)+c
__global__ __launch_bounds__(256) void k_gn_apply(float* __restrict__ xf, const float* __restrict__ par, const int mode){
  const int i = blockIdx.x*256 + threadIdx.x;
#pragma unroll
  for (int r=0;r<8;++r){
    const int idx = i + r*640000;
    float v = xf[idx];
    const int ch = idx & 127;
    if (mode == 1) v = lrelu01(v);
    v = par[ch]*v + par[128+ch];
    if (mode == 0) v = lrelu01(v);
    xf[idx] = v;
  }
}

// ---------------- final: lrelu + segment sum ----------------
__global__ __launch_bounds__(256) void k_final(const float* __restrict__ x, const int* __restrict__ bat32, float* __restrict__ outf){
  const int idx = blockIdx.x*256 + threadIdx.x;
  const int n = idx >> 7, ch = idx & 127;
  const float v = lrelu01(x[idx]);
  atomicAdd(&outf[bat32[n]*CCH + ch], v);
}

__global__ __launch_bounds__(256) void k_store(const float* __restrict__ outf, const int* __restrict__ flags, void* __restrict__ out){
  const int i = blockIdx.x*256 + threadIdx.x;
  if (i >= GG*CCH) return;
  if (flags[0]) ((float*)out)[i] = outf[i];
  else ((unsigned short*)out)[i] = f2bf(outf[i]);
}

extern "C" void kernel_launch(void* const* d_in, const int* in_sizes, int n_in,
                              void* d_out, int out_size, void* d_ws, size_t ws_size,
                              hipStream_t stream){
  const void* x_in = d_in[0];
  const void* ew   = d_in[1];
  const void* cw   = d_in[2];
  const void* wih  = d_in[3];
  const void* whh  = d_in[4];
  const void* bih  = d_in[5];
  const void* bhh  = d_in[6];
  const void* gnw  = d_in[7];
  const void* gnb  = d_in[8];
  const void* gnms = d_in[9];
  const void* eidx  = d_in[10];
  const void* batch = d_in[11];

  float* base = (float*)d_ws;
  size_t o = 0;
  float* xf     = base + o; o += (size_t)NN*CCH;   // fp32 state
  float* mbuf   = base + o; o += (size_t)NN*CCH;   // m fp32
  float* aggbuf = base + o; o += (size_t)NN*CCH;   // agg fp32
  unsigned short* wconvT= (unsigned short*)(base + o); o += CCH*CCH/2;
  unsigned short* wiB   = (unsigned short*)(base + o); o += 384*CCH/2;
  unsigned short* whB   = (unsigned short*)(base + o); o += 384*CCH/2;
  float* ewt    = base + o; o += EE;
  float* gnpar  = base + o; o += 256;
  int* flags    = (int*)(base + o); o += 2;
  int* bat32    = (int*)(base + o); o += NN;
  // ---- zero zone (one memset covers outf + gnacc + deg) ----
  float* outf   = base + o; o += GG*CCH;   // 8192
  float* gnacc  = base + o; o += 1024;     // 4 layers x 256
  int* deg      = (int*)(base + o); o += NN;
  // ---- end zero zone ----
  int* roff     = (int*)(base + o); o += NN+1;
  int* pos      = (int*)(base + o); o += NN;
  int* es       = (int*)(base + o); o += EE;

  hipMemsetAsync(outf, 0, (size_t)(GG*CCH + 1024 + NN)*4, stream);

  k_detect<<<1,256,0,stream>>>((const unsigned short*)x_in, (const unsigned int*)eidx, flags);
  k_hist<<<2500,256,0,stream>>>(eidx, flags, deg);
  k_scan<<<1,1024,0,stream>>>(deg, roff, pos);
  k_scatter<<<2500,256,0,stream>>>(eidx, ew, flags, pos, es, ewt);
  k_x2f<<<20000,256,0,stream>>>(x_in, flags, xf);
  k_batcvt<<<157,256,0,stream>>>(batch, flags, bat32);

  const int steps[5] = {5,4,3,2,1};
  for (int L=0; L<5; ++L){
    k_wcvt_bf<<<192,256,0,stream>>>(wih, flags, (size_t)L*384*CCH, wiB, 384*CCH);
    k_wcvt_bf<<<192,256,0,stream>>>(whh, flags, (size_t)L*384*CCH, whB, 384*CCH);
    for (int s=0; s<steps[L]; ++s){
      k_wconvT<<<64,256,0,stream>>>(cw, flags, (size_t)(L*5+s)*CCH*CCH, wconvT);
      k_gemm_m<<<625,256,0,stream>>>(xf, wconvT, mbuf);
      k_agg<<<10000,256,0,stream>>>(mbuf, roff, es, ewt, aggbuf, (L<4) ? 1 : 0);
      k_gru<<<625,256,0,stream>>>(aggbuf, xf, wiB, whB, bih, bhh, (size_t)L*384, flags);
    }
    if (L < 4){
      const int pre = (L==0) ? 0 : 1;
      k_gn_stats<<<313,256,0,stream>>>(xf, gnacc + L*256, pre);
      k_gn_final<<<1,128,0,stream>>>(gnacc + L*256, gnw, gnb, gnms, (size_t)L*CCH, flags, gnpar);
      k_gn_apply<<<2500,256,0,stream>>>(xf, gnpar, pre);
    }
  }
  k_final<<<20000,256,0,stream>>>(xf, bat32, outf);
  k_store<<<32,256,0,stream>>>(outf, flags, d_out);
}

// Round 5
// 2434.698 us; speedup vs baseline: 1.5878x; 1.1461x over previous
//
#include <hip/hip_runtime.h>
#include <hip/hip_bf16.h>

#define NN 40000
#define EE 640000
#define CCH 128
#define GG 64
#define WPAD 136   // LDS row stride (shorts) for 128-k weight rows: 272B -> 2-way bank aliasing (free)

typedef __attribute__((ext_vector_type(8))) short short8;
typedef __attribute__((ext_vector_type(4))) float f32x4;

__device__ __forceinline__ float lrelu01(float v){ return v > 0.f ? v : 0.01f*v; }
__device__ __forceinline__ float sigm(float v){ return 1.f/(1.f + __expf(-v)); }
__device__ __forceinline__ float tanh_f(float v){
  v = fminf(fmaxf(v, -15.f), 15.f);
  const float t = __expf(2.f*v);
  return (t - 1.f)/(t + 1.f);
}
__device__ __forceinline__ unsigned short f2bf(float f){
  union { float f; unsigned int u; } v; v.f = f;
  const unsigned int r = v.u + 0x7FFFu + ((v.u >> 16) & 1u);
  return (unsigned short)(r >> 16);
}
__device__ __forceinline__ float bf2f(unsigned short h){
  union { unsigned int u; float f; } v; v.u = ((unsigned int)h) << 16;
  return v.f;
}
// 3-term split: x = hi + mid + lo, ~24 mantissa bits (>= fp32 quality through MFMA fp32 accum)
__device__ __forceinline__ void split3(const float* __restrict__ p, short8& hi, short8& mi, short8& lo){
  const float4 a = *(const float4*)p;
  const float4 b = *(const float4*)(p + 4);
  const float v[8] = {a.x,a.y,a.z,a.w,b.x,b.y,b.z,b.w};
#pragma unroll
  for (int i=0;i<8;++i){
    const unsigned short h = f2bf(v[i]);
    const float r = v[i] - bf2f(h);
    const unsigned short m = f2bf(r);
    const float r2 = r - bf2f(m);
    hi[i] = (short)h; mi[i] = (short)m; lo[i] = (short)f2bf(r2);
  }
}
// dual-dtype loads: flags[0]=floats are f32, flags[1]=ints are i64
__device__ __forceinline__ float LDF(const void* p, int f32, size_t i){
  return f32 ? ((const float*)p)[i] : bf2f(((const unsigned short*)p)[i]);
}
__device__ __forceinline__ int LDI(const void* p, int i64, size_t i){
  return i64 ? (int)((const long long*)p)[i] : ((const int*)p)[i];
}

// ---------------- dtype detection (device-side, graph-safe) ----------------
__global__ __launch_bounds__(256) void k_detect(const unsigned short* __restrict__ xh,
                                                const unsigned int* __restrict__ ei,
                                                int* __restrict__ flags){
  __shared__ int s1[256], s2[256];
  const int t = threadIdx.x;
  int c1 = 0, c2 = 0;
  for (int i=0;i<8;++i){
    const unsigned short w = xh[t*8 + i];
    const int e = (w >> 7) & 0xFF;
    if (e < 100 || e > 140) c1++;
    const unsigned int o = ei[(t*8 + i)*2 + 1];
    if (o) c2++;
  }
  s1[t]=c1; s2[t]=c2; __syncthreads();
  for (int off=128; off; off>>=1){ if (t<off){ s1[t]+=s1[t+off]; s2[t]+=s2[t+off]; } __syncthreads(); }
  if (t==0){
    flags[0] = (s1[0] > 64) ? 1 : 0;
    flags[1] = (s2[0] < 16) ? 1 : 0;
  }
}

// ---------------- CSR build ----------------
__global__ __launch_bounds__(256) void k_hist(const void* __restrict__ eidx, const int* __restrict__ flags,
                                              int* __restrict__ deg){
  const int e = blockIdx.x*256 + threadIdx.x;
  if (e >= EE) return;
  atomicAdd(&deg[LDI(eidx, flags[1], (size_t)EE + e)], 1);
}

// hierarchical exclusive scan of deg[NN]: per-block sums -> scan of 157 -> per-block scan
__global__ __launch_bounds__(256) void k_scan1(const int* __restrict__ deg, int* __restrict__ bsum){
  __shared__ int s[256];
  const int t = threadIdx.x;
  const int i = blockIdx.x*256 + t;
  s[t] = (i < NN) ? deg[i] : 0;
  __syncthreads();
  for (int off=128; off; off>>=1){ if (t<off) s[t]+=s[t+off]; __syncthreads(); }
  if (t==0) bsum[blockIdx.x] = s[0];
}

__global__ __launch_bounds__(256) void k_scan2(const int* __restrict__ bsum, int* __restrict__ boff,
                                               int* __restrict__ roff){
  __shared__ int s[256];
  const int t = threadIdx.x;
  const int v = (t < 157) ? bsum[t] : 0;
  s[t] = v; __syncthreads();
  for (int off=1; off<256; off<<=1){
    const int u = (t>=off) ? s[t-off] : 0;
    __syncthreads(); s[t] += u; __syncthreads();
  }
  if (t < 157) boff[t] = s[t] - v;   // exclusive
  if (t == 0) roff[NN] = EE;
}

__global__ __launch_bounds__(256) void k_scan3(const int* __restrict__ deg, const int* __restrict__ boff,
                                               int* __restrict__ roff, int* __restrict__ pos){
  __shared__ int s[256];
  const int t = threadIdx.x;
  const int i = blockIdx.x*256 + t;
  const int v = (i < NN) ? deg[i] : 0;
  s[t] = v; __syncthreads();
  for (int off=1; off<256; off<<=1){
    const int u = (t>=off) ? s[t-off] : 0;
    __syncthreads(); s[t] += u; __syncthreads();
  }
  if (i < NN){
    const int ex = boff[blockIdx.x] + s[t] - v;
    roff[i] = ex; pos[i] = ex;
  }
}

__global__ __launch_bounds__(256) void k_scatter(const void* __restrict__ eidx, const void* __restrict__ ew,
                                                 const int* __restrict__ flags,
                                                 int* __restrict__ pos, int* __restrict__ es, float* __restrict__ ewt){
  const int e = blockIdx.x*256 + threadIdx.x;
  if (e >= EE) return;
  const int i64 = flags[1];
  const int d = LDI(eidx, i64, (size_t)EE + e);
  const int p = atomicAdd(&pos[d], 1);
  es[p] = LDI(eidx, i64, e);
  ewt[p] = LDF(ew, flags[0], e);
}

// ---------------- converts ----------------
__global__ __launch_bounds__(256) void k_x2f(const void* __restrict__ xin, const int* __restrict__ flags,
                                             float* __restrict__ xf){
  const int i = blockIdx.x*256 + threadIdx.x;
  if (i < NN*CCH) xf[i] = LDF(xin, flags[0], i);
}

__global__ __launch_bounds__(256) void k_batcvt(const void* __restrict__ batch, const int* __restrict__ flags,
                                                int* __restrict__ bat32){
  const int i = blockIdx.x*256 + threadIdx.x;
  if (i < NN) bat32[i] = LDI(batch, flags[1], i);
}

__global__ __launch_bounds__(256) void k_wcvt_bf(const void* __restrict__ w, const int* __restrict__ flags,
                                                 const size_t off, unsigned short* __restrict__ o, const int n){
  const int i = blockIdx.x*256 + threadIdx.x;
  if (i < n) o[i] = f2bf(LDF(w, flags[0], off + i));
}

// conv W (128x128 row-major [k][c]) -> WT bf16 [c][k]
__global__ __launch_bounds__(256) void k_wconvT(const void* __restrict__ w, const int* __restrict__ flags,
                                                const size_t off, unsigned short* __restrict__ o){
  const int i = blockIdx.x*256 + threadIdx.x;
  if (i >= CCH*CCH) return;
  const int c = i >> 7, k = i & 127;
  o[i] = f2bf(LDF(w, flags[0], off + (size_t)k*CCH + c));
}

// ---------------- m = xf @ convWT (MFMA, 3-split A, LDS-staged B) ----------------
// 16 nodes/wave, 64/block, grid 625
__global__ __launch_bounds__(256) void k_gemm_m(const float* __restrict__ xf,
                                                const unsigned short* __restrict__ wT,
                                                float* __restrict__ m){
  __shared__ unsigned short s_w[128*WPAD];   // 34 KB
  const int tid = threadIdx.x;
  const int wv = tid >> 6;
  const int lane = tid & 63;
  const int quad = lane >> 4;
  const int ln = lane & 15;
  const int m0 = blockIdx.x*64 + wv*16;
  // stage all 128 weight rows (16B units: 128 rows x 16 parts)
  for (int u = tid; u < 128*16; u += 256){
    const int c = u >> 4, part = u & 15;
    *(short8*)(s_w + c*WPAD + part*8) = *(const short8*)(wT + (size_t)c*CCH + part*8);
  }
  short8 fh[4], fm[4], fl[4];
  {
    const float* p = xf + (size_t)(m0 + ln)*CCH + quad*8;
#pragma unroll
    for (int kk=0;kk<4;++kk) split3(p + kk*32, fh[kk], fm[kk], fl[kk]);
  }
  __syncthreads();
#pragma unroll 1
  for (int ct=0; ct<8; ++ct){
    f32x4 acc = {0.f,0.f,0.f,0.f};
    const int col = ct*16 + ln;
#pragma unroll
    for (int kk=0;kk<4;++kk){
      const short8 fb = *(const short8*)(s_w + col*WPAD + kk*32 + quad*8);
      acc = __builtin_amdgcn_mfma_f32_16x16x32_bf16(fh[kk], fb, acc, 0, 0, 0);
      acc = __builtin_amdgcn_mfma_f32_16x16x32_bf16(fm[kk], fb, acc, 0, 0, 0);
      acc = __builtin_amdgcn_mfma_f32_16x16x32_bf16(fl[kk], fb, acc, 0, 0, 0);
    }
#pragma unroll
    for (int r=0;r<4;++r)
      m[(size_t)(m0 + quad*4 + r)*CCH + col] = acc[r];
  }
}

// ---------------- agg[dst] = sum ew * m[src]  (half-wave float4 gather) ----------------
__global__ __launch_bounds__(256) void k_agg(const float* __restrict__ m, const int* __restrict__ roff,
                                             const int* __restrict__ es, const float* __restrict__ ewt,
                                             float* __restrict__ agg, const int useW){
  const int node = (blockIdx.x*256 + threadIdx.x) >> 6;
  if (node >= NN) return;
  const int lane = threadIdx.x & 63;
  const int h = lane >> 5, j = lane & 31;
  const int beg = roff[node], end = roff[node+1];
  float ax=0.f, ay=0.f, az=0.f, aw=0.f;
  int e = beg + h;
  for (; e + 2 < end; e += 4){
    const int s0 = es[e], s1 = es[e+2];
    const float w0 = useW ? ewt[e] : 1.f;
    const float w1 = useW ? ewt[e+2] : 1.f;
    const float4 v0 = *(const float4*)(m + (size_t)s0*CCH + j*4);
    const float4 v1 = *(const float4*)(m + (size_t)s1*CCH + j*4);
    ax += w0*v0.x + w1*v1.x; ay += w0*v0.y + w1*v1.y;
    az += w0*v0.z + w1*v1.z; aw += w0*v0.w + w1*v1.w;
  }
  if (e < end){
    const int s0 = es[e];
    const float w0 = useW ? ewt[e] : 1.f;
    const float4 v0 = *(const float4*)(m + (size_t)s0*CCH + j*4);
    ax += w0*v0.x; ay += w0*v0.y; az += w0*v0.z; aw += w0*v0.w;
  }
  ax += __shfl_xor(ax, 32); ay += __shfl_xor(ay, 32);
  az += __shfl_xor(az, 32); aw += __shfl_xor(aw, 32);
  if (h == 0){
    float4 ov; ov.x=ax; ov.y=ay; ov.z=az; ov.w=aw;
    *(float4*)(agg + (size_t)node*CCH + j*4) = ov;
  }
}

// ---------------- fused GRU via MFMA (3-split A, LDS-staged B): x = GRU(agg, x) ----------------
// 16 nodes/wave, 64/block, grid 625; LDS 51KB -> 3 blocks/CU
__global__ __launch_bounds__(256) void k_gru(const float* __restrict__ agg,
                                             float* __restrict__ xf,
                                             const unsigned short* __restrict__ wiB,  // [384][128] bf16 (Bt)
                                             const unsigned short* __restrict__ whB,  // [384][128] bf16 (Bt)
                                             const void* __restrict__ bih, const void* __restrict__ bhh,
                                             const size_t boff, const int* __restrict__ flags){
  __shared__ unsigned short s_w[6*32*WPAD];   // 51 KB: 6 chunks (wi g0..2, wh g0..2) x 32 cols
  const int tid = threadIdx.x;
  const int wv = tid >> 6;
  const int lane = tid & 63;
  const int quad = lane >> 4;
  const int ln = lane & 15;
  const int m0 = blockIdx.x*64 + wv*16;
  const int f32 = flags[0];
  short8 fah[4], fam[4], fal[4], fxh[4], fxm[4], fxl[4];
  {
    const float* pa = agg + (size_t)(m0 + ln)*CCH + quad*8;
    const float* px = xf  + (size_t)(m0 + ln)*CCH + quad*8;
#pragma unroll
    for (int kk=0;kk<4;++kk){
      split3(pa + kk*32, fah[kk], fam[kk], fal[kk]);
      split3(px + kk*32, fxh[kk], fxm[kk], fxl[kk]);
    }
  }
#pragma unroll 1
  for (int sc=0; sc<4; ++sc){
    __syncthreads();   // prior superstep's reads done
    // stage 6 chunks x 32 cols x 128 k (16B units: 6*32*16 = 3072)
    for (int u = tid; u < 3072; u += 256){
      const int chunk = u >> 9;          // 0..5
      const int rem = u & 511;
      const int c = rem >> 4, part = rem & 15;
      const unsigned short* src = ((chunk < 3) ? wiB : whB)
          + ((size_t)(((chunk<3)?chunk:chunk-3)*CCH + sc*32 + c)*CCH + part*8);
      *(short8*)(s_w + chunk*(32*WPAD) + c*WPAD + part*8) = *(const short8*)src;
    }
    __syncthreads();
#pragma unroll 1
    for (int hf=0; hf<2; ++hf){
      const int ct = sc*2 + hf;
      const int c_local = hf*16 + ln;
      f32x4 acc[6];
#pragma unroll
      for (int g=0;g<6;++g) acc[g] = (f32x4){0.f,0.f,0.f,0.f};
#pragma unroll
      for (int kk=0;kk<4;++kk){
#pragma unroll
        for (int g=0;g<3;++g){
          const short8 fbi = *(const short8*)(s_w + g*(32*WPAD)     + c_local*WPAD + kk*32 + quad*8);
          const short8 fbh = *(const short8*)(s_w + (3+g)*(32*WPAD) + c_local*WPAD + kk*32 + quad*8);
          acc[g]   = __builtin_amdgcn_mfma_f32_16x16x32_bf16(fah[kk], fbi, acc[g], 0, 0, 0);
          acc[g]   = __builtin_amdgcn_mfma_f32_16x16x32_bf16(fam[kk], fbi, acc[g], 0, 0, 0);
          acc[g]   = __builtin_amdgcn_mfma_f32_16x16x32_bf16(fal[kk], fbi, acc[g], 0, 0, 0);
          acc[3+g] = __builtin_amdgcn_mfma_f32_16x16x32_bf16(fxh[kk], fbh, acc[3+g], 0, 0, 0);
          acc[3+g] = __builtin_amdgcn_mfma_f32_16x16x32_bf16(fxm[kk], fbh, acc[3+g], 0, 0, 0);
          acc[3+g] = __builtin_amdgcn_mfma_f32_16x16x32_bf16(fxl[kk], fbh, acc[3+g], 0, 0, 0);
        }
      }
      const int col = ct*16 + ln;
      float bi[3], bh[3];
#pragma unroll
      for (int g=0;g<3;++g){
        bi[g] = LDF(bih, f32, boff + g*CCH + col);
        bh[g] = LDF(bhh, f32, boff + g*CCH + col);
      }
#pragma unroll
      for (int r=0;r<4;++r){
        const int row = m0 + quad*4 + r;
        const size_t idx = (size_t)row*CCH + col;
        const float h = xf[idx];
        const float rr = sigm(acc[0][r] + acc[3][r] + bi[0] + bh[0]);
        const float zz = sigm(acc[1][r] + acc[4][r] + bi[1] + bh[1]);
        const float nv = tanh_f(acc[2][r] + bi[2] + rr*(acc[5][r] + bh[2]));
        xf[idx] = (1.f - zz)*nv + zz*h;
      }
    }
  }
}

// ---------------- GraphNorm ----------------
__global__ __launch_bounds__(256) void k_gn_stats(const float* __restrict__ x, float* __restrict__ accum, const int pre){
  const int tid = threadIdx.x;
  const int ch = tid & 127;
  const int half = tid >> 7;
  const int node0 = blockIdx.x * 128;
  float s = 0.f, s2 = 0.f;
  for (int r = half; r < 128; r += 2){
    const int n = node0 + r;
    if (n >= NN) break;
    float v = x[(size_t)n*CCH + ch];
    if (pre) v = lrelu01(v);
    s += v; s2 += v*v;
  }
  __shared__ float buf[256];
  buf[tid] = s; __syncthreads();
  if (tid < 128) atomicAdd(&accum[ch], buf[tid] + buf[tid+128]);
  __syncthreads();
  buf[tid] = s2; __syncthreads();
  if (tid < 128) atomicAdd(&accum[128+ch], buf[tid] + buf[tid+128]);
}

__global__ void k_gn_final(const float* __restrict__ accum, const void* __restrict__ gw,
                           const void* __restrict__ gb, const void* __restrict__ gms,
                           const size_t off, const int* __restrict__ flags, float* __restrict__ par){
  const int j = threadIdx.x;
  const int f32 = flags[0];
  const float inv = 1.f/(float)NN;
  const float mean = accum[j]*inv;
  const float m2 = accum[128+j]*inv;
  const float ms = LDF(gms, f32, off + j);
  const float var = m2 - 2.f*ms*mean*mean + ms*ms*mean*mean;
  const float sc = LDF(gw, f32, off + j) / sqrtf(var + 1e-5f);
  par[j] = sc;
  par[128+j] = LDF(gb, f32, off + j) - sc*ms*mean;
}

// mode 0: lrelu(a*x+c)   mode 1: a*lrelu(x)+c
__global__ __launch_bounds__(256) void k_gn_apply(float* __restrict__ xf, const float* __restrict__ par, const int mode){
  const int i = blockIdx.x*256 + threadIdx.x;
#pragma unroll
  for (int r=0;r<8;++r){
    const int idx = i + r*640000;
    float v = xf[idx];
    const int ch = idx & 127;
    if (mode == 1) v = lrelu01(v);
    v = par[ch]*v + par[128+ch];
    if (mode == 0) v = lrelu01(v);
    xf[idx] = v;
  }
}

// ---------------- final: lrelu + segment sum (batch sorted -> run-flush atomics) ----------------
__global__ __launch_bounds__(256) void k_final(const float* __restrict__ x, const int* __restrict__ bat,
                                               float* __restrict__ outf){
  const int t = threadIdx.x;
  const int ch = t & 127;
  const int half = t >> 7;
  const int n0 = blockIdx.x*32;
  int cur = -1; float acc = 0.f;
  for (int r = half; r < 32; r += 2){
    const int n = n0 + r;
    const int b = bat[n];
    if (b != cur){
      if (cur >= 0) atomicAdd(&outf[cur*CCH + ch], acc);
      cur = b; acc = 0.f;
    }
    acc += lrelu01(x[(size_t)n*CCH + ch]);
  }
  if (cur >= 0) atomicAdd(&outf[cur*CCH + ch], acc);
}

__global__ __launch_bounds__(256) void k_store(const float* __restrict__ outf, const int* __restrict__ flags, void* __restrict__ out){
  const int i = blockIdx.x*256 + threadIdx.x;
  if (i >= GG*CCH) return;
  if (flags[0]) ((float*)out)[i] = outf[i];
  else ((unsigned short*)out)[i] = f2bf(outf[i]);
}

extern "C" void kernel_launch(void* const* d_in, const int* in_sizes, int n_in,
                              void* d_out, int out_size, void* d_ws, size_t ws_size,
                              hipStream_t stream){
  const void* x_in = d_in[0];
  const void* ew   = d_in[1];
  const void* cw   = d_in[2];
  const void* wih  = d_in[3];
  const void* whh  = d_in[4];
  const void* bih  = d_in[5];
  const void* bhh  = d_in[6];
  const void* gnw  = d_in[7];
  const void* gnb  = d_in[8];
  const void* gnms = d_in[9];
  const void* eidx  = d_in[10];
  const void* batch = d_in[11];

  float* base = (float*)d_ws;
  size_t o = 0;
  float* xf     = base + o; o += (size_t)NN*CCH;   // fp32 state
  float* mbuf   = base + o; o += (size_t)NN*CCH;   // m fp32
  float* aggbuf = base + o; o += (size_t)NN*CCH;   // agg fp32
  unsigned short* wconvT= (unsigned short*)(base + o); o += CCH*CCH/2;
  unsigned short* wiB   = (unsigned short*)(base + o); o += 384*CCH/2;
  unsigned short* whB   = (unsigned short*)(base + o); o += 384*CCH/2;
  float* ewt    = base + o; o += EE;
  float* gnpar  = base + o; o += 256;
  int* flags    = (int*)(base + o); o += 2;
  int* bat32    = (int*)(base + o); o += NN;
  int* bsum     = (int*)(base + o); o += 160;
  int* boff2    = (int*)(base + o); o += 160;
  // ---- zero zone (one memset covers outf + gnacc + deg) ----
  float* outf   = base + o; o += GG*CCH;   // 8192
  float* gnacc  = base + o; o += 1024;     // 4 layers x 256
  int* deg      = (int*)(base + o); o += NN;
  // ---- end zero zone ----
  int* roff     = (int*)(base + o); o += NN+1;
  int* pos      = (int*)(base + o); o += NN;
  int* es       = (int*)(base + o); o += EE;

  hipMemsetAsync(outf, 0, (size_t)(GG*CCH + 1024 + NN)*4, stream);

  k_detect<<<1,256,0,stream>>>((const unsigned short*)x_in, (const unsigned int*)eidx, flags);
  k_hist<<<2500,256,0,stream>>>(eidx, flags, deg);
  k_scan1<<<157,256,0,stream>>>(deg, bsum);
  k_scan2<<<1,256,0,stream>>>(bsum, boff2, roff);
  k_scan3<<<157,256,0,stream>>>(deg, boff2, roff, pos);
  k_scatter<<<2500,256,0,stream>>>(eidx, ew, flags, pos, es, ewt);
  k_x2f<<<20000,256,0,stream>>>(x_in, flags, xf);
  k_batcvt<<<157,256,0,stream>>>(batch, flags, bat32);

  const int steps[5] = {5,4,3,2,1};
  for (int L=0; L<5; ++L){
    k_wcvt_bf<<<192,256,0,stream>>>(wih, flags, (size_t)L*384*CCH, wiB, 384*CCH);
    k_wcvt_bf<<<192,256,0,stream>>>(whh, flags, (size_t)L*384*CCH, whB, 384*CCH);
    for (int s=0; s<steps[L]; ++s){
      k_wconvT<<<64,256,0,stream>>>(cw, flags, (size_t)(L*5+s)*CCH*CCH, wconvT);
      k_gemm_m<<<625,256,0,stream>>>(xf, wconvT, mbuf);
      k_agg<<<10000,256,0,stream>>>(mbuf, roff, es, ewt, aggbuf, (L<4) ? 1 : 0);
      k_gru<<<625,256,0,stream>>>(aggbuf, xf, wiB, whB, bih, bhh, (size_t)L*384, flags);
    }
    if (L < 4){
      const int pre = (L==0) ? 0 : 1;
      k_gn_stats<<<313,256,0,stream>>>(xf, gnacc + L*256, pre);
      k_gn_final<<<1,128,0,stream>>>(gnacc + L*256, gnw, gnb, gnms, (size_t)L*CCH, flags, gnpar);
      k_gn_apply<<<2500,256,0,stream>>>(xf, gnpar, pre);
    }
  }
  k_final<<<1250,256,0,stream>>>(xf, bat32, outf);
  k_store<<<32,256,0,stream>>>(outf, flags, d_out);
}

// Round 6
// 2044.842 us; speedup vs baseline: 1.8905x; 1.1907x over previous
//
#include <hip/hip_runtime.h>
#include <hip/hip_bf16.h>

#define NN 40000
#define EE 640000
#define CCH 128
#define GG 64

typedef __attribute__((ext_vector_type(8))) short short8;
typedef __attribute__((ext_vector_type(4))) float f32x4;

__device__ __forceinline__ float lrelu01(float v){ return v > 0.f ? v : 0.01f*v; }
__device__ __forceinline__ float sigm(float v){ return 1.f/(1.f + __expf(-v)); }
__device__ __forceinline__ float tanh_f(float v){
  v = fminf(fmaxf(v, -15.f), 15.f);
  const float t = __expf(2.f*v);
  return (t - 1.f)/(t + 1.f);
}
__device__ __forceinline__ unsigned short f2bf(float f){
  union { float f; unsigned int u; } v; v.f = f;
  const unsigned int r = v.u + 0x7FFFu + ((v.u >> 16) & 1u);
  return (unsigned short)(r >> 16);
}
__device__ __forceinline__ float bf2f(unsigned short h){
  union { unsigned int u; float f; } v; v.u = ((unsigned int)h) << 16;
  return v.f;
}
// 2-term split from two pre-loaded float4s: x = hi + lo (~16-17 mantissa bits; error floor is
// set by agg ordering, verified r4 vs r5: absmax identical at 5.0 for 2- and 3-split)
__device__ __forceinline__ void split2v(const float4 a, const float4 b, short8& hi, short8& lo){
  const float v[8] = {a.x,a.y,a.z,a.w,b.x,b.y,b.z,b.w};
#pragma unroll
  for (int i=0;i<8;++i){
    const unsigned short h = f2bf(v[i]);
    hi[i] = (short)h;
    lo[i] = (short)f2bf(v[i] - bf2f(h));
  }
}
// dual-dtype loads: flags[0]=floats are f32, flags[1]=ints are i64
__device__ __forceinline__ float LDF(const void* p, int f32, size_t i){
  return f32 ? ((const float*)p)[i] : bf2f(((const unsigned short*)p)[i]);
}
__device__ __forceinline__ int LDI(const void* p, int i64, size_t i){
  return i64 ? (int)((const long long*)p)[i] : ((const int*)p)[i];
}

// ---------------- dtype detection (device-side, graph-safe) ----------------
__global__ __launch_bounds__(256) void k_detect(const unsigned short* __restrict__ xh,
                                                const unsigned int* __restrict__ ei,
                                                int* __restrict__ flags){
  __shared__ int s1[256], s2[256];
  const int t = threadIdx.x;
  int c1 = 0, c2 = 0;
  for (int i=0;i<8;++i){
    const unsigned short w = xh[t*8 + i];
    const int e = (w >> 7) & 0xFF;
    if (e < 100 || e > 140) c1++;
    const unsigned int o = ei[(t*8 + i)*2 + 1];
    if (o) c2++;
  }
  s1[t]=c1; s2[t]=c2; __syncthreads();
  for (int off=128; off; off>>=1){ if (t<off){ s1[t]+=s1[t+off]; s2[t]+=s2[t+off]; } __syncthreads(); }
  if (t==0){
    flags[0] = (s1[0] > 64) ? 1 : 0;
    flags[1] = (s2[0] < 16) ? 1 : 0;
  }
}

// ---------------- CSR build ----------------
__global__ __launch_bounds__(256) void k_hist(const void* __restrict__ eidx, const int* __restrict__ flags,
                                              int* __restrict__ deg){
  const int e = blockIdx.x*256 + threadIdx.x;
  if (e >= EE) return;
  atomicAdd(&deg[LDI(eidx, flags[1], (size_t)EE + e)], 1);
}

__global__ __launch_bounds__(256) void k_scan1(const int* __restrict__ deg, int* __restrict__ bsum){
  __shared__ int s[256];
  const int t = threadIdx.x;
  const int i = blockIdx.x*256 + t;
  s[t] = (i < NN) ? deg[i] : 0;
  __syncthreads();
  for (int off=128; off; off>>=1){ if (t<off) s[t]+=s[t+off]; __syncthreads(); }
  if (t==0) bsum[blockIdx.x] = s[0];
}

__global__ __launch_bounds__(256) void k_scan2(const int* __restrict__ bsum, int* __restrict__ boff,
                                               int* __restrict__ roff){
  __shared__ int s[256];
  const int t = threadIdx.x;
  const int v = (t < 157) ? bsum[t] : 0;
  s[t] = v; __syncthreads();
  for (int off=1; off<256; off<<=1){
    const int u = (t>=off) ? s[t-off] : 0;
    __syncthreads(); s[t] += u; __syncthreads();
  }
  if (t < 157) boff[t] = s[t] - v;   // exclusive
  if (t == 0) roff[NN] = EE;
}

__global__ __launch_bounds__(256) void k_scan3(const int* __restrict__ deg, const int* __restrict__ boff,
                                               int* __restrict__ roff, int* __restrict__ pos){
  __shared__ int s[256];
  const int t = threadIdx.x;
  const int i = blockIdx.x*256 + t;
  const int v = (i < NN) ? deg[i] : 0;
  s[t] = v; __syncthreads();
  for (int off=1; off<256; off<<=1){
    const int u = (t>=off) ? s[t-off] : 0;
    __syncthreads(); s[t] += u; __syncthreads();
  }
  if (i < NN){
    const int ex = boff[blockIdx.x] + s[t] - v;
    roff[i] = ex; pos[i] = ex;
  }
}

__global__ __launch_bounds__(256) void k_scatter(const void* __restrict__ eidx, const void* __restrict__ ew,
                                                 const int* __restrict__ flags,
                                                 int* __restrict__ pos, int* __restrict__ es, float* __restrict__ ewt){
  const int e = blockIdx.x*256 + threadIdx.x;
  if (e >= EE) return;
  const int i64 = flags[1];
  const int d = LDI(eidx, i64, (size_t)EE + e);
  const int p = atomicAdd(&pos[d], 1);
  es[p] = LDI(eidx, i64, e);
  ewt[p] = LDF(ew, flags[0], e);
}

// ---------------- converts ----------------
__global__ __launch_bounds__(256) void k_x2f(const void* __restrict__ xin, const int* __restrict__ flags,
                                             float* __restrict__ xf){
  const int i = blockIdx.x*256 + threadIdx.x;
  if (i < NN*CCH) xf[i] = LDF(xin, flags[0], i);
}

__global__ __launch_bounds__(256) void k_batcvt(const void* __restrict__ batch, const int* __restrict__ flags,
                                                int* __restrict__ bat32){
  const int i = blockIdx.x*256 + threadIdx.x;
  if (i < NN) bat32[i] = LDI(batch, flags[1], i);
}

__global__ __launch_bounds__(256) void k_wcvt_bf(const void* __restrict__ w, const int* __restrict__ flags,
                                                 const size_t off, unsigned short* __restrict__ o, const int n){
  const int i = blockIdx.x*256 + threadIdx.x;
  if (i < n) o[i] = f2bf(LDF(w, flags[0], off + i));
}

// conv W (128x128 row-major [k][c]) -> WT bf16 [c][k]
__global__ __launch_bounds__(256) void k_wconvT(const void* __restrict__ w, const int* __restrict__ flags,
                                                const size_t off, unsigned short* __restrict__ o){
  const int i = blockIdx.x*256 + threadIdx.x;
  if (i >= CCH*CCH) return;
  const int c = i >> 7, k = i & 127;
  o[i] = f2bf(LDF(w, flags[0], off + (size_t)k*CCH + c));
}

// ---------------- m = xf @ convWT (MFMA, 2-split A, XOR-swizzled LDS B) ----------------
// grid 1250: i = bx>>1 (64-node group), j = bx&1 (64-col half). One barrier per block.
__global__ __launch_bounds__(256) void k_gemm_m(const float* __restrict__ xf,
                                                const unsigned short* __restrict__ wT,
                                                float* __restrict__ m){
  __shared__ unsigned short s_w[64*128];   // 16 KB
  const int tid = threadIdx.x;
  const int wv = tid >> 6;
  const int lane = tid & 63;
  const int quad = lane >> 4;
  const int ln = lane & 15;
  const int bi_ = blockIdx.x >> 1, j = blockIdx.x & 1;
  const int m0 = bi_*64 + wv*16;
  // raw fragment loads (in flight during staging)
  float4 ra[8];
  {
    const float* p = xf + (size_t)(m0 + ln)*CCH + quad*8;
#pragma unroll
    for (int kk=0;kk<4;++kk){
      ra[kk*2]   = *(const float4*)(p + kk*32);
      ra[kk*2+1] = *(const float4*)(p + kk*32 + 4);
    }
  }
  // stage 64 cols x 128 k, XOR swizzle on 16B parts
  for (int u = tid; u < 1024; u += 256){
    const int c = u >> 4, p = u & 15;
    *(short8*)(s_w + c*128 + ((p ^ (c & 15))*8)) =
      *(const short8*)(wT + (size_t)(j*64 + c)*CCH + p*8);
  }
  short8 fh[4], fl[4];
#pragma unroll
  for (int kk=0;kk<4;++kk) split2v(ra[kk*2], ra[kk*2+1], fh[kk], fl[kk]);
  __syncthreads();
#pragma unroll 1
  for (int ct=0; ct<4; ++ct){
    f32x4 acc = {0.f,0.f,0.f,0.f};
    const int c_local = ct*16 + ln;
#pragma unroll
    for (int kk=0;kk<4;++kk){
      const short8 fb = *(const short8*)(s_w + c_local*128 + (((kk*4+quad) ^ (c_local & 15))*8));
      acc = __builtin_amdgcn_mfma_f32_16x16x32_bf16(fh[kk], fb, acc, 0, 0, 0);
      acc = __builtin_amdgcn_mfma_f32_16x16x32_bf16(fl[kk], fb, acc, 0, 0, 0);
    }
    const int col = j*64 + c_local;
#pragma unroll
    for (int r=0;r<4;++r)
      m[(size_t)(m0 + quad*4 + r)*CCH + col] = acc[r];
  }
}

// ---------------- agg[dst] = sum ew * m[src]  (FROZEN — summation order fixed since r4) ----------------
__global__ __launch_bounds__(256) void k_agg(const float* __restrict__ m, const int* __restrict__ roff,
                                             const int* __restrict__ es, const float* __restrict__ ewt,
                                             float* __restrict__ agg, const int useW){
  const int node = (blockIdx.x*256 + threadIdx.x) >> 6;
  if (node >= NN) return;
  const int lane = threadIdx.x & 63;
  const int h = lane >> 5, j = lane & 31;
  const int beg = roff[node], end = roff[node+1];
  float ax=0.f, ay=0.f, az=0.f, aw=0.f;
  int e = beg + h;
  for (; e + 2 < end; e += 4){
    const int s0 = es[e], s1 = es[e+2];
    const float w0 = useW ? ewt[e] : 1.f;
    const float w1 = useW ? ewt[e+2] : 1.f;
    const float4 v0 = *(const float4*)(m + (size_t)s0*CCH + j*4);
    const float4 v1 = *(const float4*)(m + (size_t)s1*CCH + j*4);
    ax += w0*v0.x + w1*v1.x; ay += w0*v0.y + w1*v1.y;
    az += w0*v0.z + w1*v1.z; aw += w0*v0.w + w1*v1.w;
  }
  if (e < end){
    const int s0 = es[e];
    const float w0 = useW ? ewt[e] : 1.f;
    const float4 v0 = *(const float4*)(m + (size_t)s0*CCH + j*4);
    ax += w0*v0.x; ay += w0*v0.y; az += w0*v0.z; aw += w0*v0.w;
  }
  ax += __shfl_xor(ax, 32); ay += __shfl_xor(ay, 32);
  az += __shfl_xor(az, 32); aw += __shfl_xor(aw, 32);
  if (h == 0){
    float4 ov; ov.x=ax; ov.y=ay; ov.z=az; ov.w=aw;
    *(float4*)(agg + (size_t)node*CCH + j*4) = ov;
  }
}

// ---------------- fused GRU via MFMA (2-split A, col-split blocks): x = GRU(agg, x) ----------------
// grid 2500: i = bx>>2 (64-node group), j = bx&3 (32-col group). LDS 48 KB, ONE barrier.
__global__ __launch_bounds__(256) void k_gru(const float* __restrict__ agg,
                                             float* __restrict__ xf,
                                             const unsigned short* __restrict__ wiB,  // [384][128] bf16 (Bt)
                                             const unsigned short* __restrict__ whB,  // [384][128] bf16 (Bt)
                                             const void* __restrict__ bih, const void* __restrict__ bhh,
                                             const size_t boff, const int* __restrict__ flags){
  __shared__ unsigned short s_w[6*32*128];   // 48 KB: 6 chunks (wi g0..2, wh g0..2) x 32 cols x 128 k
  const int tid = threadIdx.x;
  const int wv = tid >> 6;
  const int lane = tid & 63;
  const int quad = lane >> 4;
  const int ln = lane & 15;
  const int bi_ = blockIdx.x >> 2, j = blockIdx.x & 3;
  const int m0 = bi_*64 + wv*16;
  const int f32 = flags[0];
  // raw fragment loads (issue first, consumed after staging)
  float4 ra[8], rx[8];
  {
    const float* pa = agg + (size_t)(m0 + ln)*CCH + quad*8;
    const float* px = xf  + (size_t)(m0 + ln)*CCH + quad*8;
#pragma unroll
    for (int kk=0;kk<4;++kk){
      ra[kk*2]   = *(const float4*)(pa + kk*32);
      ra[kk*2+1] = *(const float4*)(pa + kk*32 + 4);
      rx[kk*2]   = *(const float4*)(px + kk*32);
      rx[kk*2+1] = *(const float4*)(px + kk*32 + 4);
    }
  }
  // stage 6 chunks x 32 cols x 128 k (16B units: 6*32*16 = 3072), XOR swizzle
  for (int u = tid; u < 3072; u += 256){
    const int chunk = u >> 9;            // 0..5
    const int rem = u & 511;
    const int c = rem >> 4, p = rem & 15;
    const unsigned short* src = ((chunk < 3) ? wiB : whB)
        + ((size_t)(((chunk<3)?chunk:chunk-3)*CCH + j*32 + c)*CCH + p*8);
    *(short8*)(s_w + chunk*4096 + c*128 + ((p ^ (c & 15))*8)) = *(const short8*)src;
  }
  short8 fah[4], fal[4], fxh[4], fxl[4];
#pragma unroll
  for (int kk=0;kk<4;++kk){
    split2v(ra[kk*2], ra[kk*2+1], fah[kk], fal[kk]);
    split2v(rx[kk*2], rx[kk*2+1], fxh[kk], fxl[kk]);
  }
  __syncthreads();
#pragma unroll 1
  for (int hf=0; hf<2; ++hf){
    const int c_local = hf*16 + ln;
    f32x4 acc[6];
#pragma unroll
    for (int g=0;g<6;++g) acc[g] = (f32x4){0.f,0.f,0.f,0.f};
#pragma unroll
    for (int kk=0;kk<4;++kk){
      const int sw = ((kk*4+quad) ^ (c_local & 15))*8;
#pragma unroll
      for (int g=0;g<3;++g){
        const short8 fbi = *(const short8*)(s_w + g*4096     + c_local*128 + sw);
        const short8 fbh = *(const short8*)(s_w + (3+g)*4096 + c_local*128 + sw);
        acc[g]   = __builtin_amdgcn_mfma_f32_16x16x32_bf16(fah[kk], fbi, acc[g], 0, 0, 0);
        acc[g]   = __builtin_amdgcn_mfma_f32_16x16x32_bf16(fal[kk], fbi, acc[g], 0, 0, 0);
        acc[3+g] = __builtin_amdgcn_mfma_f32_16x16x32_bf16(fxh[kk], fbh, acc[3+g], 0, 0, 0);
        acc[3+g] = __builtin_amdgcn_mfma_f32_16x16x32_bf16(fxl[kk], fbh, acc[3+g], 0, 0, 0);
      }
    }
    const int col = j*32 + c_local;
    float bi[3], bh[3];
#pragma unroll
    for (int g=0;g<3;++g){
      bi[g] = LDF(bih, f32, boff + g*CCH + col);
      bh[g] = LDF(bhh, f32, boff + g*CCH + col);
    }
#pragma unroll
    for (int r=0;r<4;++r){
      const int row = m0 + quad*4 + r;
      const size_t idx = (size_t)row*CCH + col;
      const float h = xf[idx];
      const float rr = sigm(acc[0][r] + acc[3][r] + bi[0] + bh[0]);
      const float zz = sigm(acc[1][r] + acc[4][r] + bi[1] + bh[1]);
      const float nv = tanh_f(acc[2][r] + bi[2] + rr*(acc[5][r] + bh[2]));
      xf[idx] = (1.f - zz)*nv + zz*h;
    }
  }
}

// ---------------- GraphNorm ----------------
__global__ __launch_bounds__(256) void k_gn_stats(const float* __restrict__ x, float* __restrict__ accum, const int pre){
  const int tid = threadIdx.x;
  const int ch = tid & 127;
  const int half = tid >> 7;
  const int node0 = blockIdx.x * 128;
  float s = 0.f, s2 = 0.f;
  for (int r = half; r < 128; r += 2){
    const int n = node0 + r;
    if (n >= NN) break;
    float v = x[(size_t)n*CCH + ch];
    if (pre) v = lrelu01(v);
    s += v; s2 += v*v;
  }
  __shared__ float buf[256];
  buf[tid] = s; __syncthreads();
  if (tid < 128) atomicAdd(&accum[ch], buf[tid] + buf[tid+128]);
  __syncthreads();
  buf[tid] = s2; __syncthreads();
  if (tid < 128) atomicAdd(&accum[128+ch], buf[tid] + buf[tid+128]);
}

__global__ void k_gn_final(const float* __restrict__ accum, const void* __restrict__ gw,
                           const void* __restrict__ gb, const void* __restrict__ gms,
                           const size_t off, const int* __restrict__ flags, float* __restrict__ par){
  const int j = threadIdx.x;
  const int f32 = flags[0];
  const float inv = 1.f/(float)NN;
  const float mean = accum[j]*inv;
  const float m2 = accum[128+j]*inv;
  const float ms = LDF(gms, f32, off + j);
  const float var = m2 - 2.f*ms*mean*mean + ms*ms*mean*mean;
  const float sc = LDF(gw, f32, off + j) / sqrtf(var + 1e-5f);
  par[j] = sc;
  par[128+j] = LDF(gb, f32, off + j) - sc*ms*mean;
}

// mode 0: lrelu(a*x+c)   mode 1: a*lrelu(x)+c
__global__ __launch_bounds__(256) void k_gn_apply(float* __restrict__ xf, const float* __restrict__ par, const int mode){
  const int i = blockIdx.x*256 + threadIdx.x;
#pragma unroll
  for (int r=0;r<8;++r){
    const int idx = i + r*640000;
    float v = xf[idx];
    const int ch = idx & 127;
    if (mode == 1) v = lrelu01(v);
    v = par[ch]*v + par[128+ch];
    if (mode == 0) v = lrelu01(v);
    xf[idx] = v;
  }
}

// ---------------- final: lrelu + segment sum (batch sorted -> run-flush atomics) ----------------
__global__ __launch_bounds__(256) void k_final(const float* __restrict__ x, const int* __restrict__ bat,
                                               float* __restrict__ outf){
  const int t = threadIdx.x;
  const int ch = t & 127;
  const int half = t >> 7;
  const int n0 = blockIdx.x*32;
  int cur = -1; float acc = 0.f;
  for (int r = half; r < 32; r += 2){
    const int n = n0 + r;
    const int b = bat[n];
    if (b != cur){
      if (cur >= 0) atomicAdd(&outf[cur*CCH + ch], acc);
      cur = b; acc = 0.f;
    }
    acc += lrelu01(x[(size_t)n*CCH + ch]);
  }
  if (cur >= 0) atomicAdd(&outf[cur*CCH + ch], acc);
}

__global__ __launch_bounds__(256) void k_store(const float* __restrict__ outf, const int* __restrict__ flags, void* __restrict__ out){
  const int i = blockIdx.x*256 + threadIdx.x;
  if (i >= GG*CCH) return;
  if (flags[0]) ((float*)out)[i] = outf[i];
  else ((unsigned short*)out)[i] = f2bf(outf[i]);
}

extern "C" void kernel_launch(void* const* d_in, const int* in_sizes, int n_in,
                              void* d_out, int out_size, void* d_ws, size_t ws_size,
                              hipStream_t stream){
  const void* x_in = d_in[0];
  const void* ew   = d_in[1];
  const void* cw   = d_in[2];
  const void* wih  = d_in[3];
  const void* whh  = d_in[4];
  const void* bih  = d_in[5];
  const void* bhh  = d_in[6];
  const void* gnw  = d_in[7];
  const void* gnb  = d_in[8];
  const void* gnms = d_in[9];
  const void* eidx  = d_in[10];
  const void* batch = d_in[11];

  float* base = (float*)d_ws;
  size_t o = 0;
  float* xf     = base + o; o += (size_t)NN*CCH;   // fp32 state
  float* mbuf   = base + o; o += (size_t)NN*CCH;   // m fp32
  float* aggbuf = base + o; o += (size_t)NN*CCH;   // agg fp32
  unsigned short* wconvT= (unsigned short*)(base + o); o += CCH*CCH/2;
  unsigned short* wiB   = (unsigned short*)(base + o); o += 384*CCH/2;
  unsigned short* whB   = (unsigned short*)(base + o); o += 384*CCH/2;
  float* ewt    = base + o; o += EE;
  float* gnpar  = base + o; o += 256;
  int* flags    = (int*)(base + o); o += 2;
  int* bat32    = (int*)(base + o); o += NN;
  int* bsum     = (int*)(base + o); o += 160;
  int* boff2    = (int*)(base + o); o += 160;
  // ---- zero zone (one memset covers outf + gnacc + deg) ----
  float* outf   = base + o; o += GG*CCH;   // 8192
  float* gnacc  = base + o; o += 1024;     // 4 layers x 256
  int* deg      = (int*)(base + o); o += NN;
  // ---- end zero zone ----
  int* roff     = (int*)(base + o); o += NN+1;
  int* pos      = (int*)(base + o); o += NN;
  int* es       = (int*)(base + o); o += EE;

  hipMemsetAsync(outf, 0, (size_t)(GG*CCH + 1024 + NN)*4, stream);

  k_detect<<<1,256,0,stream>>>((const unsigned short*)x_in, (const unsigned int*)eidx, flags);
  k_hist<<<2500,256,0,stream>>>(eidx, flags, deg);
  k_scan1<<<157,256,0,stream>>>(deg, bsum);
  k_scan2<<<1,256,0,stream>>>(bsum, boff2, roff);
  k_scan3<<<157,256,0,stream>>>(deg, boff2, roff, pos);
  k_scatter<<<2500,256,0,stream>>>(eidx, ew, flags, pos, es, ewt);
  k_x2f<<<20000,256,0,stream>>>(x_in, flags, xf);
  k_batcvt<<<157,256,0,stream>>>(batch, flags, bat32);

  const int steps[5] = {5,4,3,2,1};
  for (int L=0; L<5; ++L){
    k_wcvt_bf<<<192,256,0,stream>>>(wih, flags, (size_t)L*384*CCH, wiB, 384*CCH);
    k_wcvt_bf<<<192,256,0,stream>>>(whh, flags, (size_t)L*384*CCH, whB, 384*CCH);
    for (int s=0; s<steps[L]; ++s){
      k_wconvT<<<64,256,0,stream>>>(cw, flags, (size_t)(L*5+s)*CCH*CCH, wconvT);
      k_gemm_m<<<1250,256,0,stream>>>(xf, wconvT, mbuf);
      k_agg<<<10000,256,0,stream>>>(mbuf, roff, es, ewt, aggbuf, (L<4) ? 1 : 0);
      k_gru<<<2500,256,0,stream>>>(aggbuf, xf, wiB, whB, bih, bhh, (size_t)L*384, flags);
    }
    if (L < 4){
      const int pre = (L==0) ? 0 : 1;
      k_gn_stats<<<313,256,0,stream>>>(xf, gnacc + L*256, pre);
      k_gn_final<<<1,128,0,stream>>>(gnacc + L*256, gnw, gnb, gnms, (size_t)L*CCH, flags, gnpar);
      k_gn_apply<<<2500,256,0,stream>>>(xf, gnpar, pre);
    }
  }
  k_final<<<1250,256,0,stream>>>(xf, bat32, outf);
  k_store<<<32,256,0,stream>>>(outf, flags, d_out);
}